// Round 7
// baseline (752.049 us; speedup 1.0000x reference)
//
#include <hip/hip_runtime.h>
#include <hip/hip_cooperative_groups.h>
#include <math.h>

namespace cg = cooperative_groups;

#define BB 8
#define NN 2048
#define FF 256
#define NW 64            // packed u32 words per adjacency row
#define ALPHA 0.2f

typedef _Float16 f16x8 __attribute__((ext_vector_type(8)));
typedef float    f32x4 __attribute__((ext_vector_type(4)));
typedef unsigned long long u64;

__device__ __forceinline__ float lrelu(float x){ return fmaxf(x, ALPHA*x); }

// One cooperative kernel: 256 blocks x 512 threads, 1 block/CU, 16 KB LDS.
// P0: pack adj bits + x->f16 + W transpose->f16
// per layer: P1 gemm_hw (WhT,f1,f2) | P2 column softmax denom -> g | P3 gemm_att
__global__ __launch_bounds__(512, 2) void gat_mega(
    const int* __restrict__ adj, const float* __restrict__ x,
    const float* __restrict__ W0, const float* __restrict__ Wrest,
    const float* __restrict__ Avec, float* __restrict__ out,
    u64* __restrict__ packed, _Float16* __restrict__ hA, _Float16* __restrict__ hB,
    _Float16* __restrict__ WhT, _Float16* __restrict__ Wt,
    float* __restrict__ f1, float* __restrict__ f2, float* __restrict__ g)
{
    cg::grid_group grid = cg::this_grid();
    __shared__ __align__(16) char SMEM[16384];
    const int blk = blockIdx.x, t = threadIdx.x;

    // ================= P0 =================
    if (blk < 64){
        // ---- prep_w: one 64x64 tile per block; layer = blk>>4
        {
            int lw = blk >> 4, rest = blk & 15;
            int c0 = (rest >> 2)*64, k0 = (rest & 3)*64;
            const float* Win = (lw == 0) ? W0 : (Wrest + (size_t)(lw-1)*FF*FF);
            _Float16 (*Ls)[66] = (_Float16(*)[66])SMEM;
            if (t < 256){
                for (int it = 0; it < 4; ++it){
                    int idx = it*256 + t;
                    int r = idx >> 4, c4 = (idx & 15)*4;
                    float4 v = *(const float4*)&Win[(size_t)(k0 + r)*FF + c0 + c4];
                    Ls[c4+0][r] = (_Float16)v.x; Ls[c4+1][r] = (_Float16)v.y;
                    Ls[c4+2][r] = (_Float16)v.z; Ls[c4+3][r] = (_Float16)v.w;
                }
            }
            __syncthreads();
            if (t < 256){
                int c = t >> 2, jch = t & 3;
                const unsigned* lp = (const unsigned*)&Ls[c][jch*16];
                int4 o0 = make_int4(lp[0], lp[1], lp[2], lp[3]);
                int4 o1 = make_int4(lp[4], lp[5], lp[6], lp[7]);
                _Float16* dst = Wt + ((size_t)lw*FF + c0 + c)*FF + k0 + jch*16;
                *(int4*)dst = o0;
                *(int4*)(dst + 8) = o1;
            }
        }
        // ---- x -> f16 (blocks 0..63 grid-stride)
        {
            const long long nx4 = (long long)BB*NN*FF/4;
            for (long long i = (long long)blk*512 + t; i < nx4; i += 64*512){
                float4 v = ((const float4*)x)[i];
                union { _Float16 h[4]; u64 u; } cv;
                cv.h[0] = (_Float16)v.x; cv.h[1] = (_Float16)v.y;
                cv.h[2] = (_Float16)v.z; cv.h[3] = (_Float16)v.w;
                ((u64*)hA)[i] = cv.u;
            }
        }
    } else {
        // ---- pack adj bits (blocks 64..255 grid-stride, ballot per wave)
        const long long total = (long long)BB*NN*NN;
        for (long long i = (long long)(blk-64)*512 + t; i < total; i += 192*512){
            u64 m = __ballot(adj[i] > 0);
            if ((t & 63) == 0) packed[i >> 6] = m;
        }
    }
    grid.sync();

    for (int layer = 0; layer < 4; ++layer){
        const _Float16* hin = (layer & 1) ? hB : hA;
        _Float16* hnext = (layer & 1) ? hA : hB;
        const _Float16* Wl = Wt + (size_t)layer*FF*FF;
        const float* Al = Avec + (size_t)layer*2*FF;

        // ================= P1: WhT = (hin @ W)^T + f1,f2 =================
        {
            float (*fred)[64][4] = (float(*)[64][4])SMEM;
            int l = t & 63, wid = t >> 6;
            int wr = wid >> 2, wc = wid & 3;
            int lg = l >> 4, lr = l & 15;
            size_t i0 = (size_t)blk * 64;
            f32x4 acc[2][4] = {};
            for (int k0 = 0; k0 < FF; k0 += 32){
                f16x8 a[2], bf[4];
                #pragma unroll
                for (int m = 0; m < 2; ++m){
                    int4 v = *(const int4*)&hin[(i0 + wr*32 + m*16 + lr)*FF + k0 + lg*8];
                    a[m] = *(f16x8*)&v;
                }
                #pragma unroll
                for (int n = 0; n < 4; ++n){
                    int4 v = *(const int4*)&Wl[(size_t)(wc*64 + n*16 + lr)*FF + k0 + lg*8];
                    bf[n] = *(f16x8*)&v;
                }
                #pragma unroll
                for (int m = 0; m < 2; ++m)
                    #pragma unroll
                    for (int n = 0; n < 4; ++n)
                        acc[m][n] = __builtin_amdgcn_mfma_f32_16x16x32_f16(a[m], bf[n], acc[m][n], 0, 0, 0);
            }
            int b = (int)(i0 >> 11);
            int jb = (int)(i0 & (NN-1));
            _Float16* WT = WhT + (size_t)b*FF*NN;
            #pragma unroll
            for (int m = 0; m < 2; ++m){
                #pragma unroll
                for (int n = 0; n < 4; ++n){
                    int col = wc*64 + n*16 + lr;
                    int row = jb + wr*32 + m*16 + lg*4;
                    union { _Float16 h[4]; u64 u; } pk;
                    pk.h[0] = (_Float16)acc[m][n][0]; pk.h[1] = (_Float16)acc[m][n][1];
                    pk.h[2] = (_Float16)acc[m][n][2]; pk.h[3] = (_Float16)acc[m][n][3];
                    *(u64*)&WT[(size_t)col*NN + row] = pk.u;
                }
            }
            float a1v[4], a2v[4];
            #pragma unroll
            for (int n = 0; n < 4; ++n){
                a1v[n] = Al[wc*64 + n*16 + lr];
                a2v[n] = Al[FF + wc*64 + n*16 + lr];
            }
            #pragma unroll
            for (int m = 0; m < 2; ++m){
                #pragma unroll
                for (int q = 0; q < 4; ++q){
                    float p1 = 0.f, p2 = 0.f;
                    #pragma unroll
                    for (int n = 0; n < 4; ++n){
                        float v = acc[m][n][q];
                        p1 = fmaf(v, a1v[n], p1);
                        p2 = fmaf(v, a2v[n], p2);
                    }
                    #pragma unroll
                    for (int msk = 1; msk < 16; msk <<= 1){
                        p1 += __shfl_xor(p1, msk);
                        p2 += __shfl_xor(p2, msk);
                    }
                    if (lr == 0){
                        fred[0][wr*32 + m*16 + lg*4 + q][wc] = p1;
                        fred[1][wr*32 + m*16 + lg*4 + q][wc] = p2;
                    }
                }
            }
            __syncthreads();
            if (t < 128){
                int row = t & 63, f = t >> 6;
                float v = fred[f][row][0] + fred[f][row][1] + fred[f][row][2] + fred[f][row][3];
                (f ? f2 : f1)[i0 + row] = v;
            }
        }
        grid.sync();

        // ================= P2: g[b][j] = -ln( sum_i adj ? exp(lrelu(f1_i+f2_j)) : 0 ) ===========
        {
            int b2 = blk >> 5, jt = blk & 31;                  // 64 j per block
            const unsigned* pb32 = (const unsigned*)(packed + (size_t)b2*NN*(NW/2));
            const float* f1b = f1 + b2*NN;
            int jg = t & 7, ic = t >> 3;                       // 8 j-groups x 64 i-chunks
            int j0 = jt*64 + jg*8;
            float f2v[8];
            *(float4*)&f2v[0] = *(const float4*)&f2[b2*NN + j0];
            *(float4*)&f2v[4] = *(const float4*)&f2[b2*NN + j0 + 4];
            int wi = jt*2 + (jg >> 2), sh = (jg & 3)*8;
            float acc[8] = {};
            for (int ii = 0; ii < 32; ++ii){
                int i = ic*32 + ii;
                unsigned w = pb32[(size_t)i*NW + wi] >> sh;
                float f1v = f1b[i];
                #pragma unroll
                for (int e = 0; e < 8; ++e){
                    float xv = f1v + f2v[e];
                    float p = __expf(fmaxf(xv, ALPHA*xv));
                    acc[e] += ((w >> e) & 1u) ? p : 0.f;
                }
            }
            float (*sred)[64] = (float(*)[64])SMEM;
            #pragma unroll
            for (int e = 0; e < 8; ++e) sred[ic][jg*8 + e] = acc[e];
            __syncthreads();
            if (t < 64){
                float s = 0.f;
                #pragma unroll
                for (int icc = 0; icc < 64; ++icc) s += sred[icc][t];
                g[b2*NN + jt*64 + t] = -__logf(s);
            }
            __syncthreads();   // SMEM reused by P3
        }
        grid.sync();

        // ================= P3: hout = lrelu( P' @ WhT^T ), B direct from L2, P' via LDS dbuf ====
        {
            char* Ps0 = SMEM;
            char* Ps1 = SMEM + 8192;
            int l = t & 63, wc = t >> 6;       // 8 waves = 8 col-groups of 32
            int lg = l >> 4, lr = l & 15;
            int b3 = blk & 7;
            int i0 = (blk >> 3) * 64;
            const _Float16* WT = WhT + (size_t)b3*FF*NN;
            const u64* pb = packed + (size_t)b3*NN*(NW/2);
            const float* f1b = f1 + b3*NN;
            const float* f2b = f2 + b3*NN;
            const float* gb  = g  + b3*NN;
            int prow = t >> 3, pch = t & 7;
            float f1v = f1b[i0 + prow];
            const u64* prowp = pb + (size_t)(i0 + prow)*(NW/2);
            int pso = prow*128 + ((pch << 4) ^ ((prow & 7) << 4));
            int bcol = wc*32 + lr;

            f32x4 acc[4][2] = {};
            int4 breg[2][4];
            float fv[2][8], gv2[2][8];
            unsigned w8[2];

            #define PLOAD(ks_, pp) do{ int j0_ = (ks_)*64;                                          \
                _Pragma("unroll")                                                                   \
                for (int n = 0; n < 2; ++n)                                                         \
                  _Pragma("unroll")                                                                 \
                  for (int kk = 0; kk < 2; ++kk)                                                    \
                    breg[pp][n*2+kk] = *(const int4*)&WT[(size_t)(bcol + n*16)*NN + j0_ + kk*32 + lg*8]; \
                w8[pp] = (unsigned)(prowp[ks_] >> (pch*8)) & 0xffu;                                 \
                int jb_ = j0_ + pch*8;                                                              \
                *(float4*)&fv[pp][0]  = *(const float4*)&f2b[jb_];                                  \
                *(float4*)&fv[pp][4]  = *(const float4*)&f2b[jb_+4];                                \
                *(float4*)&gv2[pp][0] = *(const float4*)&gb[jb_];                                   \
                *(float4*)&gv2[pp][4] = *(const float4*)&gb[jb_+4];                                 \
            }while(0)

            #define PWRITE(pp, pbase) do{                                                           \
                f16x8 pv_;                                                                          \
                _Pragma("unroll")                                                                   \
                for (int e = 0; e < 8; ++e){                                                        \
                    float xv_ = f1v + fv[pp][e];                                                    \
                    float p_ = __expf(fmaxf(xv_, ALPHA*xv_) + gv2[pp][e]);                          \
                    pv_[e] = (_Float16)(((w8[pp] >> e) & 1u) ? p_ : 0.f);                           \
                }                                                                                   \
                *(f16x8*)((pbase) + pso) = pv_;                                                     \
            }while(0)

            #define CONSUME(pp, pbase) do{                                                          \
                f16x8 pa_[4][2];                                                                    \
                _Pragma("unroll")                                                                   \
                for (int m = 0; m < 4; ++m){                                                        \
                    int row_ = m*16 + lr;                                                           \
                    _Pragma("unroll")                                                               \
                    for (int kk = 0; kk < 2; ++kk)                                                  \
                        pa_[m][kk] = *(const f16x8*)((pbase) + row_*128 + ((((kk*4+lg) << 4)) ^ ((row_ & 7) << 4))); \
                }                                                                                   \
                _Pragma("unroll")                                                                   \
                for (int n = 0; n < 2; ++n)                                                         \
                  _Pragma("unroll")                                                                 \
                  for (int kk = 0; kk < 2; ++kk){                                                   \
                    f16x8 bf_ = *(const f16x8*)&breg[pp][n*2+kk];                                   \
                    _Pragma("unroll")                                                               \
                    for (int m = 0; m < 4; ++m)                                                     \
                        acc[m][n] = __builtin_amdgcn_mfma_f32_16x16x32_f16(pa_[m][kk], bf_, acc[m][n], 0, 0, 0); \
                  }                                                                                 \
            }while(0)

            PLOAD(0, 0);
            PWRITE(0, Ps0);
            __syncthreads();
            for (int ks2 = 0; ks2 < 16; ++ks2){
                PLOAD(2*ks2 + 1, 1);
                CONSUME(0, Ps0);
                PWRITE(1, Ps1);
                __syncthreads();
                if (ks2 < 15) PLOAD(2*ks2 + 2, 0);
                CONSUME(1, Ps1);
                if (ks2 < 15) PWRITE(0, Ps0);
                __syncthreads();
            }
            #undef PLOAD
            #undef PWRITE
            #undef CONSUME

            size_t obase = (size_t)b3*NN*FF;
            #pragma unroll
            for (int m = 0; m < 4; ++m){
                #pragma unroll
                for (int q = 0; q < 4; ++q){
                    size_t row = i0 + m*16 + lg*4 + q;
                    #pragma unroll
                    for (int n = 0; n < 2; ++n){
                        int col = wc*32 + n*16 + lr;
                        float v = lrelu(acc[m][n][q]);
                        if (layer == 3) out[obase + row*FF + col] = v;
                        else            hnext[obase + row*FF + col] = (_Float16)v;
                    }
                }
            }
        }
        if (layer < 3) grid.sync();
    }
}

// ----------------------------------------------------------------
extern "C" void kernel_launch(void* const* d_in, const int* in_sizes, int n_in,
                              void* d_out, int out_size, void* d_ws, size_t ws_size,
                              hipStream_t stream){
    const float* x     = (const float*)d_in[0];
    const int*   adj   = (const int*)  d_in[1];
    const float* W0    = (const float*)d_in[2];
    const float* Wrest = (const float*)d_in[3];
    const float* A     = (const float*)d_in[4];
    float* outp = (float*)d_out;

    char* ws = (char*)d_ws;
    size_t off = 0;
    auto carve = [&](size_t bytes) -> void* {
        void* p = ws + off;
        off += (bytes + 255) & ~(size_t)255;
        return p;
    };
    u64*      packed = (u64*)     carve((size_t)BB*NN*NN/8);
    _Float16* hA     = (_Float16*)carve((size_t)BB*NN*FF*2);
    _Float16* hB     = (_Float16*)carve((size_t)BB*NN*FF*2);
    _Float16* WhT    = (_Float16*)carve((size_t)BB*NN*FF*2);
    _Float16* Wt     = (_Float16*)carve((size_t)4*FF*FF*2);
    float*    f1     = (float*)   carve((size_t)BB*NN*4);
    float*    f2     = (float*)   carve((size_t)BB*NN*4);
    float*    gbuf   = (float*)   carve((size_t)BB*NN*4);

    void* kargs[] = {
        (void*)&adj, (void*)&x, (void*)&W0, (void*)&Wrest, (void*)&A, (void*)&outp,
        (void*)&packed, (void*)&hA, (void*)&hB, (void*)&WhT, (void*)&Wt,
        (void*)&f1, (void*)&f2, (void*)&gbuf
    };
    hipLaunchCooperativeKernel((const void*)gat_mega, dim3(256), dim3(512),
                               kargs, 0, stream);
}

// Round 8
// 335.514 us; speedup vs baseline: 2.2415x; 2.2415x over previous
//
#include <hip/hip_runtime.h>
#include <math.h>

#define BB 8
#define NN 2048
#define FF 256
#define NW 64            // packed u32 words per adjacency row
#define ALPHA 0.2f

typedef _Float16 f16x8 __attribute__((ext_vector_type(8)));
typedef float    f32x4 __attribute__((ext_vector_type(4)));
typedef unsigned long long u64;

__device__ __forceinline__ float lrelu(float x){ return fmaxf(x, ALPHA*x); }

// ---------------------------------------------------------------- pack adj bits + x->f16 + prep W
__global__ void pack_prep(const int* __restrict__ adj, u64* __restrict__ packed,
                          const float* __restrict__ x, _Float16* __restrict__ h0,
                          const float* __restrict__ W0, const float* __restrict__ Wrest,
                          _Float16* __restrict__ Wt){
    __shared__ _Float16 Ls[64][66];
    int blk = blockIdx.x, t = threadIdx.x;
    if (blk < 64){
        // W (fp32 [k][c]) -> Wt (f16 [c][k]); one 64x64 tile per block, layer = blk>>4
        int lw = blk >> 4, rest = blk & 15;
        int c0 = (rest >> 2)*64, k0 = (rest & 3)*64;
        const float* Win = (lw == 0) ? W0 : (Wrest + (size_t)(lw-1)*FF*FF);
        for (int it = 0; it < 4; ++it){
            int idx = it*256 + t;
            int r = idx >> 4, c4 = (idx & 15)*4;
            float4 v = *(const float4*)&Win[(size_t)(k0 + r)*FF + c0 + c4];
            Ls[c4+0][r] = (_Float16)v.x; Ls[c4+1][r] = (_Float16)v.y;
            Ls[c4+2][r] = (_Float16)v.z; Ls[c4+3][r] = (_Float16)v.w;
        }
        __syncthreads();
        int c = t >> 2, jch = t & 3;
        const unsigned* lp = (const unsigned*)&Ls[c][jch*16];
        int4 o0 = make_int4(lp[0], lp[1], lp[2], lp[3]);
        int4 o1 = make_int4(lp[4], lp[5], lp[6], lp[7]);
        _Float16* dst = Wt + ((size_t)lw*FF + c0 + c)*FF + k0 + jch*16;
        *(int4*)dst = o0;
        *(int4*)(dst + 8) = o1;
    }
    long long idx = (long long)blk*blockDim.x + t;
    long long stride = (long long)gridDim.x*blockDim.x;
    const long long total = (long long)BB*NN*NN;
    for (long long i = idx; i < total; i += stride){
        u64 m = __ballot(adj[i] > 0);
        if ((t & 63) == 0) packed[i >> 6] = m;
    }
    const long long nx4 = (long long)BB*NN*FF/4;
    for (long long i = idx; i < nx4; i += stride){
        float4 v = ((const float4*)x)[i];
        union { _Float16 h[4]; u64 u; } cv;
        cv.h[0] = (_Float16)v.x; cv.h[1] = (_Float16)v.y;
        cv.h[2] = (_Float16)v.z; cv.h[3] = (_Float16)v.w;
        ((u64*)h0)[i] = cv.u;
    }
}

// ---------------------------------------------------------------- WhT = (h @ W)^T (f16 MFMA) + fused f1,f2
__global__ __launch_bounds__(512,2) void gemm_hw(const _Float16* __restrict__ hin,
        const _Float16* __restrict__ Wt, const float* __restrict__ Avec,
        _Float16* __restrict__ WhT, float* __restrict__ f1, float* __restrict__ f2){
    __shared__ float fred[2][64][4];
    int t = threadIdx.x, l = t & 63, wid = t >> 6;
    int wr = wid >> 2, wc = wid & 3;
    int lg = l >> 4, lr = l & 15;
    size_t i0 = (size_t)blockIdx.x * 64;
    f32x4 acc[2][4] = {};
    for (int k0 = 0; k0 < FF; k0 += 32){
        f16x8 a[2], bf[4];
        #pragma unroll
        for (int m = 0; m < 2; ++m){
            int4 v = *(const int4*)&hin[(i0 + wr*32 + m*16 + lr)*FF + k0 + lg*8];
            a[m] = *(f16x8*)&v;
        }
        #pragma unroll
        for (int n = 0; n < 4; ++n){
            int4 v = *(const int4*)&Wt[(size_t)(wc*64 + n*16 + lr)*FF + k0 + lg*8];
            bf[n] = *(f16x8*)&v;
        }
        #pragma unroll
        for (int m = 0; m < 2; ++m)
            #pragma unroll
            for (int n = 0; n < 4; ++n)
                acc[m][n] = __builtin_amdgcn_mfma_f32_16x16x32_f16(a[m], bf[n], acc[m][n], 0, 0, 0);
    }
    int b  = (int)(i0 >> 11);
    int jb = (int)(i0 & (NN-1));
    _Float16* WT = WhT + (size_t)b*FF*NN;
    #pragma unroll
    for (int m = 0; m < 2; ++m){
        #pragma unroll
        for (int n = 0; n < 4; ++n){
            int col = wc*64 + n*16 + lr;
            int row = jb + wr*32 + m*16 + lg*4;
            union { _Float16 h[4]; u64 u; } pk;
            pk.h[0] = (_Float16)acc[m][n][0]; pk.h[1] = (_Float16)acc[m][n][1];
            pk.h[2] = (_Float16)acc[m][n][2]; pk.h[3] = (_Float16)acc[m][n][3];
            *(u64*)&WT[(size_t)col*NN + row] = pk.u;
        }
    }
    float a1v[4], a2v[4];
    #pragma unroll
    for (int n = 0; n < 4; ++n){
        a1v[n] = Avec[wc*64 + n*16 + lr];
        a2v[n] = Avec[FF + wc*64 + n*16 + lr];
    }
    #pragma unroll
    for (int m = 0; m < 2; ++m){
        #pragma unroll
        for (int q = 0; q < 4; ++q){
            float p1 = 0.f, p2 = 0.f;
            #pragma unroll
            for (int n = 0; n < 4; ++n){
                float v = acc[m][n][q];
                p1 = fmaf(v, a1v[n], p1);
                p2 = fmaf(v, a2v[n], p2);
            }
            #pragma unroll
            for (int msk = 1; msk < 16; msk <<= 1){
                p1 += __shfl_xor(p1, msk);
                p2 += __shfl_xor(p2, msk);
            }
            if (lr == 0){
                fred[0][wr*32 + m*16 + lg*4 + q][wc] = p1;
                fred[1][wr*32 + m*16 + lg*4 + q][wc] = p2;
            }
        }
    }
    __syncthreads();
    if (t < 128){
        int row = t & 63, f = t >> 6;
        float v = fred[f][row][0] + fred[f][row][1] + fred[f][row][2] + fred[f][row][3];
        (f ? f2 : f1)[i0 + row] = v;
    }
}

// ---------------------------------------------------------------- g[b][j] = -ln( sum_i adj ? exp(lrelu(f1_i+f2_j)) : 0 )
// 256 blocks x 512 thr: block = (b, 64-j tile); full i-sweep, LDS tree reduce. (mega-P2, proven)
__global__ __launch_bounds__(512,2) void spass_g(const u64* __restrict__ packed,
        const float* __restrict__ f1, const float* __restrict__ f2, float* __restrict__ g){
    __shared__ float sred[64][64];
    int blk = blockIdx.x, t = threadIdx.x;
    int b2 = blk >> 5, jt = blk & 31;
    const unsigned* pb32 = (const unsigned*)(packed + (size_t)b2*NN*(NW/2));
    const float* f1b = f1 + b2*NN;
    int jg = t & 7, ic = t >> 3;
    int j0 = jt*64 + jg*8;
    float f2v[8];
    *(float4*)&f2v[0] = *(const float4*)&f2[b2*NN + j0];
    *(float4*)&f2v[4] = *(const float4*)&f2[b2*NN + j0 + 4];
    int wi = jt*2 + (jg >> 2), sh = (jg & 3)*8;
    float acc[8] = {};
    for (int ii = 0; ii < 32; ++ii){
        int i = ic*32 + ii;
        unsigned w = pb32[(size_t)i*NW + wi] >> sh;
        float f1v = f1b[i];
        #pragma unroll
        for (int e = 0; e < 8; ++e){
            float xv = f1v + f2v[e];
            float p = __expf(fmaxf(xv, ALPHA*xv));
            acc[e] += ((w >> e) & 1u) ? p : 0.f;
        }
    }
    #pragma unroll
    for (int e = 0; e < 8; ++e) sred[ic][jg*8 + e] = acc[e];
    __syncthreads();
    if (t < 64){
        float s = 0.f;
        #pragma unroll
        for (int icc = 0; icc < 64; ++icc) s += sred[icc][t];
        g[b2*NN + jt*64 + t] = -__logf(s);
    }
}

// ---------------------------------------------------------------- hout = lrelu( P' @ WhT^T ), P' built in LDS
// 2-phase pipelined; tile 64 rows x 128 cols (col-split); 48 KB LDS -> 2 blocks/CU at grid 512.
// blk decode: b = blk&7 (XCD), seq = blk>>3: strip = seq>>1, colhalf = seq&1.
__global__ __launch_bounds__(512,2) void gemm_att(const _Float16* __restrict__ WhT,
        const u64* __restrict__ packed64, const float* __restrict__ f1,
        const float* __restrict__ f2, const float* __restrict__ g,
        _Float16* __restrict__ hnext, float* __restrict__ out, int last){
    __shared__ char Bs[2][16384];
    __shared__ char Ps[2][8192];
    int t = threadIdx.x, l = t & 63, wid = t >> 6;
    int wr = wid >> 2, wc = wid & 3;        // 2 row-groups x 4 col-groups (wave tile 32x32)
    int lg = l >> 4, lr = l & 15;
    int b   = blockIdx.x & 7;
    int seq = blockIdx.x >> 3;
    int i0  = (seq >> 1) * 64;
    int c0  = (seq & 1) * 128;
    const _Float16* WT = WhT + (size_t)b*FF*NN + (size_t)c0*NN;
    const u64* pb = packed64 + (size_t)b*NN*(NW/2);
    const float* f2b = f2 + b*NN;
    const float* gb  = g  + b*NN;
    // P-gen: thread owns (row = t>>3, 8 j's at (t&7)*8) of the 64x64 P tile
    int prow = t >> 3;
    int pch  = t & 7;
    float f1v = f1[b*NN + i0 + prow];
    const u64* prowp = pb + (size_t)(i0 + prow)*(NW/2);
    int pso = prow*128 + ((pch << 4) ^ ((prow & 7) << 4));
    // B-stage: col = t>>2 (128 cols), chunks (t&3) and (t&3)+4
    int bcol = t >> 2, bch0 = t & 3;

    int4 bstg[2];
    float fv[8], gv[8];
    unsigned w8;

    #define STAGE_LOAD(ks_) do{ int j0_ = (ks_)*64;                                   \
        bstg[0] = *(const int4*)&WT[(size_t)bcol*NN + j0_ + bch0*8];                  \
        bstg[1] = *(const int4*)&WT[(size_t)bcol*NN + j0_ + (bch0+4)*8];              \
        w8 = (unsigned)(prowp[ks_] >> (pch*8)) & 0xffu;                               \
        int jb_ = j0_ + pch*8;                                                        \
        *(float4*)&fv[0] = *(const float4*)&f2b[jb_];                                 \
        *(float4*)&fv[4] = *(const float4*)&f2b[jb_+4];                               \
        *(float4*)&gv[0] = *(const float4*)&gb[jb_];                                  \
        *(float4*)&gv[4] = *(const float4*)&gb[jb_+4];                                \
    }while(0)

    #define STAGE_WRITE(buf_) do{                                                     \
        f16x8 pv_;                                                                    \
        _Pragma("unroll")                                                             \
        for (int e = 0; e < 8; ++e){                                                  \
            float xv_ = f1v + fv[e];                                                  \
            float p_ = __expf(fmaxf(xv_, ALPHA*xv_) + gv[e]);                         \
            pv_[e] = (_Float16)(((w8 >> e) & 1u) ? p_ : 0.f);                         \
        }                                                                             \
        *(f16x8*)(Ps[buf_] + pso) = pv_;                                              \
        *(int4*)(Bs[buf_] + (bcol << 7) + ((bch0 << 4) ^ ((bcol & 7) << 4))) = bstg[0];       \
        *(int4*)(Bs[buf_] + (bcol << 7) + (((bch0+4) << 4) ^ ((bcol & 7) << 4))) = bstg[1];   \
    }while(0)

    f32x4 acc[2][2] = {};
    STAGE_LOAD(0);
    STAGE_WRITE(0);
    __syncthreads();
    for (int ks = 0; ks < 32; ++ks){
        int cur = ks & 1;
        if (ks < 31) STAGE_LOAD(ks+1);
        f16x8 pa[2][2];
        #pragma unroll
        for (int m = 0; m < 2; ++m){
            int row = wr*32 + m*16 + lr;
            #pragma unroll
            for (int kk = 0; kk < 2; ++kk)
                pa[m][kk] = *(const f16x8*)(Ps[cur] + row*128 + (((kk*4 + lg) << 4) ^ ((row & 7) << 4)));
        }
        #pragma unroll
        for (int n = 0; n < 2; ++n){
            int col = wc*32 + n*16 + lr;
            #pragma unroll
            for (int kk = 0; kk < 2; ++kk){
                f16x8 bf = *(const f16x8*)(Bs[cur] + (col << 7) + ((kk*64 + lg*16) ^ ((col & 7) << 4)));
                #pragma unroll
                for (int m = 0; m < 2; ++m)
                    acc[m][n] = __builtin_amdgcn_mfma_f32_16x16x32_f16(pa[m][kk], bf, acc[m][n], 0, 0, 0);
            }
        }
        if (ks < 31) STAGE_WRITE(cur ^ 1);   // other buffer: no hazard with this step's reads
        __syncthreads();                      // orders write -> next step's reads
    }
    #undef STAGE_LOAD
    #undef STAGE_WRITE

    size_t obase = (size_t)b*NN*FF;
    #pragma unroll
    for (int m = 0; m < 2; ++m){
        #pragma unroll
        for (int q = 0; q < 4; ++q){
            size_t row = i0 + wr*32 + m*16 + lg*4 + q;
            #pragma unroll
            for (int n = 0; n < 2; ++n){
                int col = c0 + wc*32 + n*16 + lr;
                float v = lrelu(acc[m][n][q]);
                if (last) out[obase + row*FF + col] = v;
                else      hnext[obase + row*FF + col] = (_Float16)v;
            }
        }
    }
}

// ----------------------------------------------------------------
extern "C" void kernel_launch(void* const* d_in, const int* in_sizes, int n_in,
                              void* d_out, int out_size, void* d_ws, size_t ws_size,
                              hipStream_t stream){
    const float* x     = (const float*)d_in[0];
    const int*   adj   = (const int*)  d_in[1];
    const float* W0    = (const float*)d_in[2];
    const float* Wrest = (const float*)d_in[3];
    const float* A     = (const float*)d_in[4];
    float* out = (float*)d_out;

    char* ws = (char*)d_ws;
    size_t off = 0;
    auto carve = [&](size_t bytes) -> void* {
        void* p = ws + off;
        off += (bytes + 255) & ~(size_t)255;
        return p;
    };
    u64*      packed = (u64*)     carve((size_t)BB*NN*NN/8);
    _Float16* hA     = (_Float16*)carve((size_t)BB*NN*FF*2);
    _Float16* hB     = (_Float16*)carve((size_t)BB*NN*FF*2);
    _Float16* WhT    = (_Float16*)carve((size_t)BB*NN*FF*2);
    _Float16* Wt     = (_Float16*)carve((size_t)4*FF*FF*2);
    float*    f1     = (float*)   carve((size_t)BB*NN*4);
    float*    f2     = (float*)   carve((size_t)BB*NN*4);
    float*    g      = (float*)   carve((size_t)BB*NN*4);

    pack_prep<<<2048, 256, 0, stream>>>(adj, packed, x, hA, W0, Wrest, Wt);

    _Float16* bufs[2] = {hA, hB};
    const _Float16* hin = hA;
    for (int layer = 0; layer < 4; ++layer){
        const float* Al = A + (size_t)layer*2*FF;
        gemm_hw<<<256, 512, 0, stream>>>(hin, Wt + (size_t)layer*FF*FF, Al, WhT, f1, f2);
        spass_g<<<256, 512, 0, stream>>>(packed, f1, f2, g);
        int last = (layer == 3);
        _Float16* hnext = bufs[(layer + 1) & 1];
        gemm_att<<<512, 512, 0, stream>>>(WhT, packed, f1, f2, g, hnext, out, last);
        hin = hnext;
    }
}

// Round 9
// 315.964 us; speedup vs baseline: 2.3802x; 1.0619x over previous
//
#include <hip/hip_runtime.h>
#include <math.h>

#define BB 8
#define NN 2048
#define FF 256
#define NW 64            // packed u32 words per adjacency row
#define ALPHA 0.2f

typedef _Float16 f16x8 __attribute__((ext_vector_type(8)));
typedef float    f32x4 __attribute__((ext_vector_type(4)));
typedef unsigned long long u64;

__device__ __forceinline__ float lrelu(float x){ return fmaxf(x, ALPHA*x); }

// ---------------------------------------------------------------- pack adj bits + x->f16 + prep W
__global__ void pack_prep(const int* __restrict__ adj, u64* __restrict__ packed,
                          const float* __restrict__ x, _Float16* __restrict__ h0,
                          const float* __restrict__ W0, const float* __restrict__ Wrest,
                          _Float16* __restrict__ Wt){
    __shared__ _Float16 Ls[64][66];
    int blk = blockIdx.x, t = threadIdx.x;
    if (blk < 64){
        // W (fp32 [k][c]) -> Wt (f16 [c][k]); one 64x64 tile per block, layer = blk>>4
        int lw = blk >> 4, rest = blk & 15;
        int c0 = (rest >> 2)*64, k0 = (rest & 3)*64;
        const float* Win = (lw == 0) ? W0 : (Wrest + (size_t)(lw-1)*FF*FF);
        for (int it = 0; it < 4; ++it){
            int idx = it*256 + t;
            int r = idx >> 4, c4 = (idx & 15)*4;
            float4 v = *(const float4*)&Win[(size_t)(k0 + r)*FF + c0 + c4];
            Ls[c4+0][r] = (_Float16)v.x; Ls[c4+1][r] = (_Float16)v.y;
            Ls[c4+2][r] = (_Float16)v.z; Ls[c4+3][r] = (_Float16)v.w;
        }
        __syncthreads();
        int c = t >> 2, jch = t & 3;
        const unsigned* lp = (const unsigned*)&Ls[c][jch*16];
        int4 o0 = make_int4(lp[0], lp[1], lp[2], lp[3]);
        int4 o1 = make_int4(lp[4], lp[5], lp[6], lp[7]);
        _Float16* dst = Wt + ((size_t)lw*FF + c0 + c)*FF + k0 + jch*16;
        *(int4*)dst = o0;
        *(int4*)(dst + 8) = o1;
    }
    long long idx = (long long)blk*blockDim.x + t;
    long long stride = (long long)gridDim.x*blockDim.x;
    const long long total = (long long)BB*NN*NN;
    for (long long i = idx; i < total; i += stride){
        u64 m = __ballot(adj[i] > 0);
        if ((t & 63) == 0) packed[i >> 6] = m;
    }
    const long long nx4 = (long long)BB*NN*FF/4;
    for (long long i = idx; i < nx4; i += stride){
        float4 v = ((const float4*)x)[i];
        union { _Float16 h[4]; u64 u; } cv;
        cv.h[0] = (_Float16)v.x; cv.h[1] = (_Float16)v.y;
        cv.h[2] = (_Float16)v.z; cv.h[3] = (_Float16)v.w;
        ((u64*)h0)[i] = cv.u;
    }
}

// ---------------------------------------------------------------- Wh = h @ W (f16 MFMA) -> B' fragment-major + fused f1,f2
// B' layout: per b, 16 col-tiles (c16) x 64 k-blocks (kb) of 1 KB chunks; within a chunk,
// lane l = lg*16+lr holds (col = c16*16+lr, k = kb*32 + lg*8 + e), e = 0..7 (2B each).
__global__ __launch_bounds__(512,2) void gemm_hw(const _Float16* __restrict__ hin,
        const _Float16* __restrict__ Wt, const float* __restrict__ Avec,
        char* __restrict__ Bp, float* __restrict__ f1, float* __restrict__ f2){
    __shared__ float fred[2][64][4];
    int t = threadIdx.x, l = t & 63, wid = t >> 6;
    int wr = wid >> 2, wc = wid & 3;
    int lg = l >> 4, lr = l & 15;
    size_t i0 = (size_t)blockIdx.x * 64;
    f32x4 acc[2][4] = {};
    for (int k0 = 0; k0 < FF; k0 += 32){
        f16x8 a[2], bf[4];
        #pragma unroll
        for (int m = 0; m < 2; ++m){
            int4 v = *(const int4*)&hin[(i0 + wr*32 + m*16 + lr)*FF + k0 + lg*8];
            a[m] = *(f16x8*)&v;
        }
        #pragma unroll
        for (int n = 0; n < 4; ++n){
            int4 v = *(const int4*)&Wt[(size_t)(wc*64 + n*16 + lr)*FF + k0 + lg*8];
            bf[n] = *(f16x8*)&v;
        }
        #pragma unroll
        for (int m = 0; m < 2; ++m)
            #pragma unroll
            for (int n = 0; n < 4; ++n)
                acc[m][n] = __builtin_amdgcn_mfma_f32_16x16x32_f16(a[m], bf[n], acc[m][n], 0, 0, 0);
    }
    // fragment-major B' store: value acc[m][n][q] lives at (col = wc*64+n*16+lr, k = i0l + wr*32 + m*16 + lg*4 + q)
    int b   = (int)(i0 >> 11);
    int i0l = (int)(i0 & (NN-1));
    char* Bpb = Bp + ((size_t)b << 20);            // b * 16*64*1024
    int kb  = (i0l >> 5) + wr;
    #pragma unroll
    for (int m = 0; m < 2; ++m){
        int lgp = m*2 + (lg >> 1);
        int eb  = (lg & 1)*4;
        #pragma unroll
        for (int n = 0; n < 4; ++n){
            union { _Float16 h[4]; u64 u; } pk;
            pk.h[0] = (_Float16)acc[m][n][0]; pk.h[1] = (_Float16)acc[m][n][1];
            pk.h[2] = (_Float16)acc[m][n][2]; pk.h[3] = (_Float16)acc[m][n][3];
            int c16 = wc*4 + n;
            size_t off = ((size_t)(c16*64 + kb) << 10) + (size_t)((lgp*16 + lr)*16 + eb*2);
            *(u64*)(Bpb + off) = pk.u;
        }
    }
    // fused f1/f2 (fp32 from accumulators)
    float a1v[4], a2v[4];
    #pragma unroll
    for (int n = 0; n < 4; ++n){
        a1v[n] = Avec[wc*64 + n*16 + lr];
        a2v[n] = Avec[FF + wc*64 + n*16 + lr];
    }
    #pragma unroll
    for (int m = 0; m < 2; ++m){
        #pragma unroll
        for (int q = 0; q < 4; ++q){
            float p1 = 0.f, p2 = 0.f;
            #pragma unroll
            for (int n = 0; n < 4; ++n){
                float v = acc[m][n][q];
                p1 = fmaf(v, a1v[n], p1);
                p2 = fmaf(v, a2v[n], p2);
            }
            #pragma unroll
            for (int msk = 1; msk < 16; msk <<= 1){
                p1 += __shfl_xor(p1, msk);
                p2 += __shfl_xor(p2, msk);
            }
            if (lr == 0){
                fred[0][wr*32 + m*16 + lg*4 + q][wc] = p1;
                fred[1][wr*32 + m*16 + lg*4 + q][wc] = p2;
            }
        }
    }
    __syncthreads();
    if (t < 128){
        int row = t & 63, f = t >> 6;
        float v = fred[f][row][0] + fred[f][row][1] + fred[f][row][2] + fred[f][row][3];
        (f ? f2 : f1)[i0 + row] = v;
    }
}

// ---------------------------------------------------------------- g[b][j] = -ln( sum_i adj ? exp(lrelu(f1_i+f2_j)) : 0 )
__global__ __launch_bounds__(512,2) void spass_g(const u64* __restrict__ packed,
        const float* __restrict__ f1, const float* __restrict__ f2, float* __restrict__ g){
    __shared__ float sred[64][64];
    int blk = blockIdx.x, t = threadIdx.x;
    int b2 = blk >> 5, jt = blk & 31;
    const unsigned* pb32 = (const unsigned*)(packed + (size_t)b2*NN*(NW/2));
    const float* f1b = f1 + b2*NN;
    int jg = t & 7, ic = t >> 3;
    int j0 = jt*64 + jg*8;
    float f2v[8];
    *(float4*)&f2v[0] = *(const float4*)&f2[b2*NN + j0];
    *(float4*)&f2v[4] = *(const float4*)&f2[b2*NN + j0 + 4];
    int wi = jt*2 + (jg >> 2), sh = (jg & 3)*8;
    float acc[8] = {};
    for (int ii = 0; ii < 32; ++ii){
        int i = ic*32 + ii;
        unsigned w = pb32[(size_t)i*NW + wi] >> sh;
        float f1v = f1b[i];
        #pragma unroll
        for (int e = 0; e < 8; ++e){
            float xv = f1v + f2v[e];
            float p = __expf(fmaxf(xv, ALPHA*xv));
            acc[e] += ((w >> e) & 1u) ? p : 0.f;
        }
    }
    #pragma unroll
    for (int e = 0; e < 8; ++e) sred[ic][jg*8 + e] = acc[e];
    __syncthreads();
    if (t < 64){
        float s = 0.f;
        #pragma unroll
        for (int icc = 0; icc < 64; ++icc) s += sred[icc][t];
        g[b2*NN + jt*64 + t] = -__logf(s);
    }
}

// ---------------------------------------------------------------- hout = lrelu( P' @ Wh ): B' direct from L2, P' in LDS
// tile 64 rows x 256 cols; 8 waves (wr2 x wc4, wave tile 32x64); grid 256: b = blk&7 (XCD-local B' panel).
// B fragments: coalesced 1 KB chunk loads, double-buffered in NAMED reg sets (static indexing).
__global__ __launch_bounds__(512,2) void gemm_att(const char* __restrict__ Bp,
        const u64* __restrict__ packed64, const float* __restrict__ f1,
        const float* __restrict__ f2, const float* __restrict__ g,
        _Float16* __restrict__ hnext, float* __restrict__ out, int last){
    __shared__ char Ps0[8192];
    __shared__ char Ps1[8192];
    int t = threadIdx.x, l = t & 63, wid = t >> 6;
    int wr = wid >> 2, wc = wid & 3;
    int lg = l >> 4, lr = l & 15;
    int b  = blockIdx.x & 7;
    int i0 = (blockIdx.x >> 3) * 64;
    const char* Bpw = Bp + ((size_t)b << 20) + ((size_t)(wc*4*64) << 10) + (size_t)(l << 4);
    const u64* pb = packed64 + (size_t)b*NN*(NW/2);
    const float* f2b = f2 + b*NN;
    const float* gb  = g  + b*NN;
    // P-gen: thread owns (row = t>>3, 8 j's at (t&7)*8) of the 64x64 P tile
    int prow = t >> 3, pch = t & 7;
    float f1v = f1[b*NN + i0 + prow];
    const u64* prowp = pb + (size_t)(i0 + prow)*(NW/2);
    int pso = prow*128 + ((pch << 4) ^ ((prow & 7) << 4));

    int4 brega[8], bregb[8];
    float fv[8], gv[8];
    unsigned w8;
    f32x4 acc[2][4] = {};

    #define LOADB(reg_, ks_) do{                                                       \
        _Pragma("unroll")                                                              \
        for (int n = 0; n < 4; ++n)                                                    \
          _Pragma("unroll")                                                            \
          for (int kk = 0; kk < 2; ++kk)                                               \
            reg_[n*2+kk] = *(const int4*)(Bpw + (((size_t)(n*64 + (ks_)*2 + kk)) << 10)); \
    }while(0)

    #define LOADP(ks_) do{                                                             \
        w8 = (unsigned)(prowp[ks_] >> (pch*8)) & 0xffu;                                \
        int jb_ = (ks_)*64 + pch*8;                                                    \
        *(float4*)&fv[0] = *(const float4*)&f2b[jb_];                                  \
        *(float4*)&fv[4] = *(const float4*)&f2b[jb_+4];                                \
        *(float4*)&gv[0] = *(const float4*)&gb[jb_];                                   \
        *(float4*)&gv[4] = *(const float4*)&gb[jb_+4];                                 \
    }while(0)

    #define WRITEP(pbase_) do{                                                         \
        f16x8 pv_;                                                                     \
        _Pragma("unroll")                                                              \
        for (int e = 0; e < 8; ++e){                                                   \
            float xv_ = f1v + fv[e];                                                   \
            float p_ = __expf(fmaxf(xv_, ALPHA*xv_) + gv[e]);                          \
            pv_[e] = (_Float16)(((w8 >> e) & 1u) ? p_ : 0.f);                          \
        }                                                                              \
        *(f16x8*)((pbase_) + pso) = pv_;                                               \
    }while(0)

    #define MFMA_STEP(reg_, pbase_) do{                                                \
        f16x8 pa_[2][2];                                                               \
        _Pragma("unroll")                                                              \
        for (int m = 0; m < 2; ++m){                                                   \
            int row_ = wr*32 + m*16 + lr;                                              \
            _Pragma("unroll")                                                          \
            for (int kk = 0; kk < 2; ++kk)                                             \
                pa_[m][kk] = *(const f16x8*)((pbase_) + row_*128 + (((kk*4 + lg) << 4) ^ ((row_ & 7) << 4))); \
        }                                                                              \
        _Pragma("unroll")                                                              \
        for (int n = 0; n < 4; ++n)                                                    \
          _Pragma("unroll")                                                            \
          for (int kk = 0; kk < 2; ++kk){                                              \
            f16x8 bf_ = *(const f16x8*)&reg_[n*2+kk];                                  \
            _Pragma("unroll")                                                          \
            for (int m = 0; m < 2; ++m)                                                \
                acc[m][n] = __builtin_amdgcn_mfma_f32_16x16x32_f16(pa_[m][kk], bf_, acc[m][n], 0, 0, 0); \
          }                                                                            \
    }while(0)

    LOADB(brega, 0); LOADP(0); WRITEP(Ps0);
    __syncthreads();
    for (int ks2 = 0; ks2 < 16; ++ks2){
        int s = 2*ks2;
        // even step s: consume brega/Ps0; prefetch s+1 into bregb; P for s+1 -> Ps1
        LOADB(bregb, s+1); LOADP(s+1);
        MFMA_STEP(brega, Ps0);
        WRITEP(Ps1);
        __syncthreads();
        // odd step s+1: consume bregb/Ps1; prefetch s+2 into brega; P for s+2 -> Ps0
        if (ks2 < 15){ LOADB(brega, s+2); LOADP(s+2); }
        MFMA_STEP(bregb, Ps1);
        if (ks2 < 15){ WRITEP(Ps0); __syncthreads(); }
    }
    #undef LOADB
    #undef LOADP
    #undef WRITEP
    #undef MFMA_STEP

    size_t obase = (size_t)b*NN*FF;
    #pragma unroll
    for (int m = 0; m < 2; ++m){
        #pragma unroll
        for (int q = 0; q < 4; ++q){
            size_t row = i0 + wr*32 + m*16 + lg*4 + q;
            #pragma unroll
            for (int n = 0; n < 4; ++n){
                int col = wc*64 + n*16 + lr;
                float v = lrelu(acc[m][n][q]);
                if (last) out[obase + row*FF + col] = v;
                else      hnext[obase + row*FF + col] = (_Float16)v;
            }
        }
    }
}

// ----------------------------------------------------------------
extern "C" void kernel_launch(void* const* d_in, const int* in_sizes, int n_in,
                              void* d_out, int out_size, void* d_ws, size_t ws_size,
                              hipStream_t stream){
    const float* x     = (const float*)d_in[0];
    const int*   adj   = (const int*)  d_in[1];
    const float* W0    = (const float*)d_in[2];
    const float* Wrest = (const float*)d_in[3];
    const float* A     = (const float*)d_in[4];
    float* out = (float*)d_out;

    char* ws = (char*)d_ws;
    size_t off = 0;
    auto carve = [&](size_t bytes) -> void* {
        void* p = ws + off;
        off += (bytes + 255) & ~(size_t)255;
        return p;
    };
    u64*      packed = (u64*)     carve((size_t)BB*NN*NN/8);
    _Float16* hA     = (_Float16*)carve((size_t)BB*NN*FF*2);
    _Float16* hB     = (_Float16*)carve((size_t)BB*NN*FF*2);
    char*     Bp     = (char*)    carve((size_t)BB*NN*FF*2);   // fragment-major Wh panels
    _Float16* Wt     = (_Float16*)carve((size_t)4*FF*FF*2);
    float*    f1     = (float*)   carve((size_t)BB*NN*4);
    float*    f2     = (float*)   carve((size_t)BB*NN*4);
    float*    g      = (float*)   carve((size_t)BB*NN*4);

    pack_prep<<<2048, 256, 0, stream>>>(adj, packed, x, hA, W0, Wrest, Wt);

    _Float16* bufs[2] = {hA, hB};
    const _Float16* hin = hA;
    for (int layer = 0; layer < 4; ++layer){
        const float* Al = A + (size_t)layer*2*FF;
        gemm_hw<<<256, 512, 0, stream>>>(hin, Wt + (size_t)layer*FF*FF, Al, Bp, f1, f2);
        spass_g<<<256, 512, 0, stream>>>(packed, f1, f2, g);
        int last = (layer == 3);
        _Float16* hnext = bufs[(layer + 1) & 1];
        gemm_att<<<256, 512, 0, stream>>>(Bp, packed, f1, f2, g, hnext, out, last);
        hin = hnext;
    }
}

// Round 10
// 273.847 us; speedup vs baseline: 2.7462x; 1.1538x over previous
//
#include <hip/hip_runtime.h>
#include <math.h>

#define BB 8
#define NN 2048
#define FF 256
#define NW 64            // packed u32 words per adjacency row
#define ALPHA 0.2f

typedef _Float16 f16x8 __attribute__((ext_vector_type(8)));
typedef float    f32x4 __attribute__((ext_vector_type(4)));
typedef unsigned long long u64;

__device__ __forceinline__ float lrelu(float x){ return fmaxf(x, ALPHA*x); }

// ---------------------------------------------------------------- pack adj bits + x->f16 + prep W
__global__ void pack_prep(const int* __restrict__ adj, u64* __restrict__ packed,
                          const float* __restrict__ x, _Float16* __restrict__ h0,
                          const float* __restrict__ W0, const float* __restrict__ Wrest,
                          _Float16* __restrict__ Wt){
    __shared__ _Float16 Ls[64][66];
    int blk = blockIdx.x, t = threadIdx.x;
    if (blk < 64){
        // W (fp32 [k][c]) -> Wt (f16 [c][k]); one 64x64 tile per block, layer = blk>>4
        int lw = blk >> 4, rest = blk & 15;
        int c0 = (rest >> 2)*64, k0 = (rest & 3)*64;
        const float* Win = (lw == 0) ? W0 : (Wrest + (size_t)(lw-1)*FF*FF);
        for (int it = 0; it < 4; ++it){
            int idx = it*256 + t;
            int r = idx >> 4, c4 = (idx & 15)*4;
            float4 v = *(const float4*)&Win[(size_t)(k0 + r)*FF + c0 + c4];
            Ls[c4+0][r] = (_Float16)v.x; Ls[c4+1][r] = (_Float16)v.y;
            Ls[c4+2][r] = (_Float16)v.z; Ls[c4+3][r] = (_Float16)v.w;
        }
        __syncthreads();
        int c = t >> 2, jch = t & 3;
        const unsigned* lp = (const unsigned*)&Ls[c][jch*16];
        int4 o0 = make_int4(lp[0], lp[1], lp[2], lp[3]);
        int4 o1 = make_int4(lp[4], lp[5], lp[6], lp[7]);
        _Float16* dst = Wt + ((size_t)lw*FF + c0 + c)*FF + k0 + jch*16;
        *(int4*)dst = o0;
        *(int4*)(dst + 8) = o1;
    }
    long long idx = (long long)blk*blockDim.x + t;
    long long stride = (long long)gridDim.x*blockDim.x;
    const long long total = (long long)BB*NN*NN;
    for (long long i = idx; i < total; i += stride){
        u64 m = __ballot(adj[i] > 0);
        if ((t & 63) == 0) packed[i >> 6] = m;
    }
    const long long nx4 = (long long)BB*NN*FF/4;
    for (long long i = idx; i < nx4; i += stride){
        float4 v = ((const float4*)x)[i];
        union { _Float16 h[4]; u64 u; } cv;
        cv.h[0] = (_Float16)v.x; cv.h[1] = (_Float16)v.y;
        cv.h[2] = (_Float16)v.z; cv.h[3] = (_Float16)v.w;
        ((u64*)h0)[i] = cv.u;
    }
}

// ---------------------------------------------------------------- Wh = h @ W (f16 MFMA) -> B' fragment-major + fused f1,f2
// B' layout: per b, 16 col-tiles (c16) x 64 k-blocks (kb) of 1 KB chunks; within a chunk,
// lane l = lg*16+lr holds (col = c16*16+lr, k = kb*32 + lg*8 + e), e = 0..7 (2B each).
__global__ __launch_bounds__(512,2) void gemm_hw(const _Float16* __restrict__ hin,
        const _Float16* __restrict__ Wt, const float* __restrict__ Avec,
        char* __restrict__ Bp, float* __restrict__ f1, float* __restrict__ f2){
    __shared__ float fred[2][64][4];
    int t = threadIdx.x, l = t & 63, wid = t >> 6;
    int wr = wid >> 2, wc = wid & 3;
    int lg = l >> 4, lr = l & 15;
    size_t i0 = (size_t)blockIdx.x * 64;
    f32x4 acc[2][4] = {};
    for (int k0 = 0; k0 < FF; k0 += 32){
        f16x8 a[2], bf[4];
        #pragma unroll
        for (int m = 0; m < 2; ++m){
            int4 v = *(const int4*)&hin[(i0 + wr*32 + m*16 + lr)*FF + k0 + lg*8];
            a[m] = *(f16x8*)&v;
        }
        #pragma unroll
        for (int n = 0; n < 4; ++n){
            int4 v = *(const int4*)&Wt[(size_t)(wc*64 + n*16 + lr)*FF + k0 + lg*8];
            bf[n] = *(f16x8*)&v;
        }
        #pragma unroll
        for (int m = 0; m < 2; ++m)
            #pragma unroll
            for (int n = 0; n < 4; ++n)
                acc[m][n] = __builtin_amdgcn_mfma_f32_16x16x32_f16(a[m], bf[n], acc[m][n], 0, 0, 0);
    }
    // fragment-major B' store: value acc[m][n][q] lives at (col = wc*64+n*16+lr, k = i0l + wr*32 + m*16 + lg*4 + q)
    int b   = (int)(i0 >> 11);
    int i0l = (int)(i0 & (NN-1));
    char* Bpb = Bp + ((size_t)b << 20);            // b * 16*64*1024
    int kb  = (i0l >> 5) + wr;
    #pragma unroll
    for (int m = 0; m < 2; ++m){
        int lgp = m*2 + (lg >> 1);
        int eb  = (lg & 1)*4;
        #pragma unroll
        for (int n = 0; n < 4; ++n){
            union { _Float16 h[4]; u64 u; } pk;
            pk.h[0] = (_Float16)acc[m][n][0]; pk.h[1] = (_Float16)acc[m][n][1];
            pk.h[2] = (_Float16)acc[m][n][2]; pk.h[3] = (_Float16)acc[m][n][3];
            int c16 = wc*4 + n;
            size_t off = ((size_t)(c16*64 + kb) << 10) + (size_t)((lgp*16 + lr)*16 + eb*2);
            *(u64*)(Bpb + off) = pk.u;
        }
    }
    // fused f1/f2 (fp32 from accumulators)
    float a1v[4], a2v[4];
    #pragma unroll
    for (int n = 0; n < 4; ++n){
        a1v[n] = Avec[wc*64 + n*16 + lr];
        a2v[n] = Avec[FF + wc*64 + n*16 + lr];
    }
    #pragma unroll
    for (int m = 0; m < 2; ++m){
        #pragma unroll
        for (int q = 0; q < 4; ++q){
            float p1 = 0.f, p2 = 0.f;
            #pragma unroll
            for (int n = 0; n < 4; ++n){
                float v = acc[m][n][q];
                p1 = fmaf(v, a1v[n], p1);
                p2 = fmaf(v, a2v[n], p2);
            }
            #pragma unroll
            for (int msk = 1; msk < 16; msk <<= 1){
                p1 += __shfl_xor(p1, msk);
                p2 += __shfl_xor(p2, msk);
            }
            if (lr == 0){
                fred[0][wr*32 + m*16 + lg*4 + q][wc] = p1;
                fred[1][wr*32 + m*16 + lg*4 + q][wc] = p2;
            }
        }
    }
    __syncthreads();
    if (t < 128){
        int row = t & 63, f = t >> 6;
        float v = fred[f][row][0] + fred[f][row][1] + fred[f][row][2] + fred[f][row][3];
        (f ? f2 : f1)[i0 + row] = v;
    }
}

// ---------------------------------------------------------------- g[b][j] = -ln( sum_i adj ? exp(lrelu(f1_i+f2_j)) : 0 )
__global__ __launch_bounds__(512,2) void spass_g(const u64* __restrict__ packed,
        const float* __restrict__ f1, const float* __restrict__ f2, float* __restrict__ g){
    __shared__ float sred[64][64];
    int blk = blockIdx.x, t = threadIdx.x;
    int b2 = blk >> 5, jt = blk & 31;
    const unsigned* pb32 = (const unsigned*)(packed + (size_t)b2*NN*(NW/2));
    const float* f1b = f1 + b2*NN;
    int jg = t & 7, ic = t >> 3;
    int j0 = jt*64 + jg*8;
    float f2v[8];
    *(float4*)&f2v[0] = *(const float4*)&f2[b2*NN + j0];
    *(float4*)&f2v[4] = *(const float4*)&f2[b2*NN + j0 + 4];
    int wi = jt*2 + (jg >> 2), sh = (jg & 3)*8;
    float acc[8] = {};
    for (int ii = 0; ii < 32; ++ii){
        int i = ic*32 + ii;
        unsigned w = pb32[(size_t)i*NW + wi] >> sh;
        float f1v = f1b[i];
        #pragma unroll
        for (int e = 0; e < 8; ++e){
            float xv = f1v + f2v[e];
            float p = __expf(fmaxf(xv, ALPHA*xv));
            acc[e] += ((w >> e) & 1u) ? p : 0.f;
        }
    }
    #pragma unroll
    for (int e = 0; e < 8; ++e) sred[ic][jg*8 + e] = acc[e];
    __syncthreads();
    if (t < 64){
        float s = 0.f;
        #pragma unroll
        for (int icc = 0; icc < 64; ++icc) s += sred[icc][t];
        g[b2*NN + jt*64 + t] = -__logf(s);
    }
}

// ---------------------------------------------------------------- hout = lrelu( P' @ Wh ): B' direct from L2, P' in LDS
// tile 64 rows x 256 cols; 8 waves, wave tile 64x32 (NO B duplication); grid 256: b = blk&7.
// f2/g pre-staged in LDS (FG); B fragments double-buffered in NAMED reg sets (static indexing).
__global__ __launch_bounds__(512,2) void gemm_att(const char* __restrict__ Bp,
        const u64* __restrict__ packed64, const float* __restrict__ f1,
        const float* __restrict__ f2, const float* __restrict__ g,
        _Float16* __restrict__ hnext, float* __restrict__ out, int last){
    __shared__ char Ps0[8192];
    __shared__ char Ps1[8192];
    __shared__ float FG[2][NN];      // FG[0]=f2(b), FG[1]=g(b): 16 KB, loaded once
    int t = threadIdx.x, l = t & 63, wid = t >> 6;
    int lg = l >> 4, lr = l & 15;
    int b  = blockIdx.x & 7;
    int i0 = (blockIdx.x >> 3) * 64;
    const char* Bpw = Bp + ((size_t)b << 20) + ((size_t)(wid*2*64) << 10) + (size_t)(l << 4);
    const u64* pb = packed64 + (size_t)b*NN*(NW/2);
    // stage f2,g for this batch into LDS (512 thr x float4 covers 2048 floats each)
    ((float4*)&FG[0][0])[t] = ((const float4*)(f2 + b*NN))[t];
    ((float4*)&FG[1][0])[t] = ((const float4*)(g  + b*NN))[t];
    // P-gen: thread owns (row = t>>3, 8 j's at (t&7)*8) of the 64x64 P tile
    int prow = t >> 3, pch = t & 7;
    float f1v = f1[b*NN + i0 + prow];
    const u64* prowp = pb + (size_t)(i0 + prow)*(NW/2);
    int pso = prow*128 + ((pch << 4) ^ ((prow & 7) << 4));

    int4 brega[4], bregb[4];
    float fv[8], gv[8];
    unsigned w8;
    f32x4 acc[4][2] = {};

    #define LOADB(reg_, ks_) do{                                                       \
        _Pragma("unroll")                                                              \
        for (int n = 0; n < 2; ++n)                                                    \
          _Pragma("unroll")                                                            \
          for (int kk = 0; kk < 2; ++kk)                                               \
            reg_[n*2+kk] = *(const int4*)(Bpw + (((size_t)(n*64 + (ks_)*2 + kk)) << 10)); \
    }while(0)

    #define LOADP(ks_) do{                                                             \
        w8 = (unsigned)(prowp[ks_] >> (pch*8)) & 0xffu;                                \
        int jb_ = (ks_)*64 + pch*8;                                                    \
        *(float4*)&fv[0] = *(const float4*)&FG[0][jb_];                                \
        *(float4*)&fv[4] = *(const float4*)&FG[0][jb_+4];                              \
        *(float4*)&gv[0] = *(const float4*)&FG[1][jb_];                                \
        *(float4*)&gv[4] = *(const float4*)&FG[1][jb_+4];                              \
    }while(0)

    #define WRITEP(pbase_) do{                                                         \
        f16x8 pv_;                                                                     \
        _Pragma("unroll")                                                              \
        for (int e = 0; e < 8; ++e){                                                   \
            float xv_ = f1v + fv[e];                                                   \
            float p_ = __expf(fmaxf(xv_, ALPHA*xv_) + gv[e]);                          \
            pv_[e] = (_Float16)(((w8 >> e) & 1u) ? p_ : 0.f);                          \
        }                                                                              \
        *(f16x8*)((pbase_) + pso) = pv_;                                               \
    }while(0)

    #define MFMA_STEP(reg_, pbase_) do{                                                \
        f16x8 pa_[4][2];                                                               \
        _Pragma("unroll")                                                              \
        for (int m = 0; m < 4; ++m){                                                   \
            int row_ = m*16 + lr;                                                      \
            _Pragma("unroll")                                                          \
            for (int kk = 0; kk < 2; ++kk)                                             \
                pa_[m][kk] = *(const f16x8*)((pbase_) + row_*128 + (((kk*4 + lg) << 4) ^ ((row_ & 7) << 4))); \
        }                                                                              \
        _Pragma("unroll")                                                              \
        for (int n = 0; n < 2; ++n)                                                    \
          _Pragma("unroll")                                                            \
          for (int kk = 0; kk < 2; ++kk){                                              \
            f16x8 bf_ = *(const f16x8*)&reg_[n*2+kk];                                  \
            _Pragma("unroll")                                                          \
            for (int m = 0; m < 4; ++m)                                                \
                acc[m][n] = __builtin_amdgcn_mfma_f32_16x16x32_f16(pa_[m][kk], bf_, acc[m][n], 0, 0, 0); \
          }                                                                            \
    }while(0)

    LOADB(brega, 0);
    __syncthreads();                 // FG staged (also covers nothing else)
    LOADP(0); WRITEP(Ps0);
    __syncthreads();
    for (int ks2 = 0; ks2 < 16; ++ks2){
        int s = 2*ks2;
        // even step: consume brega/Ps0; prefetch s+1 into bregb; P(s+1) -> Ps1
        LOADB(bregb, s+1); LOADP(s+1);
        MFMA_STEP(brega, Ps0);
        WRITEP(Ps1);
        __syncthreads();
        // odd step: consume bregb/Ps1; prefetch s+2 into brega; P(s+2) -> Ps0
        if (ks2 < 15){ LOADB(brega, s+2); LOADP(s+2); }
        MFMA_STEP(bregb, Ps1);
        if (ks2 < 15){ WRITEP(Ps0); __syncthreads(); }
    }
    #undef LOADB
    #undef LOADP
    #undef WRITEP
    #undef MFMA_STEP

    size_t obase = (size_t)b*NN*FF;
    #pragma unroll
    for (int m = 0; m < 4; ++m){
        #pragma unroll
        for (int q = 0; q < 4; ++q){
            size_t row = i0 + m*16 + lg*4 + q;
            #pragma unroll
            for (int n = 0; n < 2; ++n){
                int col = wid*32 + n*16 + lr;
                float v = lrelu(acc[m][n][q]);
                if (last) out[obase + row*FF + col] = v;
                else      hnext[obase + row*FF + col] = (_Float16)v;
            }
        }
    }
}

// ----------------------------------------------------------------
extern "C" void kernel_launch(void* const* d_in, const int* in_sizes, int n_in,
                              void* d_out, int out_size, void* d_ws, size_t ws_size,
                              hipStream_t stream){
    const float* x     = (const float*)d_in[0];
    const int*   adj   = (const int*)  d_in[1];
    const float* W0    = (const float*)d_in[2];
    const float* Wrest = (const float*)d_in[3];
    const float* A     = (const float*)d_in[4];
    float* out = (float*)d_out;

    char* ws = (char*)d_ws;
    size_t off = 0;
    auto carve = [&](size_t bytes) -> void* {
        void* p = ws + off;
        off += (bytes + 255) & ~(size_t)255;
        return p;
    };
    u64*      packed = (u64*)     carve((size_t)BB*NN*NN/8);
    _Float16* hA     = (_Float16*)carve((size_t)BB*NN*FF*2);
    _Float16* hB     = (_Float16*)carve((size_t)BB*NN*FF*2);
    char*     Bp     = (char*)    carve((size_t)BB*NN*FF*2);   // fragment-major Wh panels
    _Float16* Wt     = (_Float16*)carve((size_t)4*FF*FF*2);
    float*    f1     = (float*)   carve((size_t)BB*NN*4);
    float*    f2     = (float*)   carve((size_t)BB*NN*4);
    float*    g      = (float*)   carve((size_t)BB*NN*4);

    pack_prep<<<2048, 256, 0, stream>>>(adj, packed, x, hA, W0, Wrest, Wt);

    _Float16* bufs[2] = {hA, hB};
    const _Float16* hin = hA;
    for (int layer = 0; layer < 4; ++layer){
        const float* Al = A + (size_t)layer*2*FF;
        gemm_hw<<<256, 512, 0, stream>>>(hin, Wt + (size_t)layer*FF*FF, Al, Bp, f1, f2);
        spass_g<<<256, 512, 0, stream>>>(packed, f1, f2, g);
        int last = (layer == 3);
        _Float16* hnext = bufs[(layer + 1) & 1];
        gemm_att<<<256, 512, 0, stream>>>(Bp, packed, f1, f2, g, hnext, out, last);
        hin = hnext;
    }
}

// Round 13
// 239.572 us; speedup vs baseline: 3.1391x; 1.1431x over previous
//
#include <hip/hip_runtime.h>
#include <math.h>

#define BB 8
#define NN 2048
#define FF 256
#define NW 64            // packed u32 words per adjacency row
#define ALPHA 0.2f
#define L2E 1.44269504f  // log2(e)

typedef _Float16 f16x8 __attribute__((ext_vector_type(8)));
typedef __fp16   h16x2 __attribute__((ext_vector_type(2)));
typedef float    f32x4 __attribute__((ext_vector_type(4)));
typedef unsigned long long u64;

__device__ __forceinline__ float lrelu(float x){ return fmaxf(x, ALPHA*x); }

// ---------------------------------------------------------------- pack adj bits + x->f16 + prep W
__global__ void pack_prep(const int* __restrict__ adj, u64* __restrict__ packed,
                          const float* __restrict__ x, _Float16* __restrict__ h0,
                          const float* __restrict__ W0, const float* __restrict__ Wrest,
                          _Float16* __restrict__ Wt){
    __shared__ _Float16 Ls[64][66];
    int blk = blockIdx.x, t = threadIdx.x;
    if (blk < 64){
        // W (fp32 [k][c]) -> Wt (f16 [c][k]); one 64x64 tile per block, layer = blk>>4
        int lw = blk >> 4, rest = blk & 15;
        int c0 = (rest >> 2)*64, k0 = (rest & 3)*64;
        const float* Win = (lw == 0) ? W0 : (Wrest + (size_t)(lw-1)*FF*FF);
        for (int it = 0; it < 4; ++it){
            int idx = it*256 + t;
            int r = idx >> 4, c4 = (idx & 15)*4;
            float4 v = *(const float4*)&Win[(size_t)(k0 + r)*FF + c0 + c4];
            Ls[c4+0][r] = (_Float16)v.x; Ls[c4+1][r] = (_Float16)v.y;
            Ls[c4+2][r] = (_Float16)v.z; Ls[c4+3][r] = (_Float16)v.w;
        }
        __syncthreads();
        int c = t >> 2, jch = t & 3;
        const unsigned* lp = (const unsigned*)&Ls[c][jch*16];
        int4 o0 = make_int4(lp[0], lp[1], lp[2], lp[3]);
        int4 o1 = make_int4(lp[4], lp[5], lp[6], lp[7]);
        _Float16* dst = Wt + ((size_t)lw*FF + c0 + c)*FF + k0 + jch*16;
        *(int4*)dst = o0;
        *(int4*)(dst + 8) = o1;
    }
    long long idx = (long long)blk*blockDim.x + t;
    long long stride = (long long)gridDim.x*blockDim.x;
    const long long total = (long long)BB*NN*NN;
    for (long long i = idx; i < total; i += stride){
        u64 m = __ballot(adj[i] > 0);
        if ((t & 63) == 0) packed[i >> 6] = m;
    }
    const long long nx4 = (long long)BB*NN*FF/4;
    for (long long i = idx; i < nx4; i += stride){
        float4 v = ((const float4*)x)[i];
        union { _Float16 h[4]; u64 u; } cv;
        cv.h[0] = (_Float16)v.x; cv.h[1] = (_Float16)v.y;
        cv.h[2] = (_Float16)v.z; cv.h[3] = (_Float16)v.w;
        ((u64*)h0)[i] = cv.u;
    }
}

// ---------------------------------------------------------------- Wh = h @ W (f16 MFMA) -> B' fragment-major + fused f1,f2
// B' layout: per b, 16 col-tiles (c16) x 64 k-blocks (kb) of 1 KB chunks; within a chunk,
// lane l = lg*16+lr holds (col = c16*16+lr, k = kb*32 + lg*8 + e), e = 0..7 (2B each).
// f1,f2 are written PRE-SCALED by log2(e) (exp2 rebasing).
__global__ __launch_bounds__(512,2) void gemm_hw(const _Float16* __restrict__ hin,
        const _Float16* __restrict__ Wt, const float* __restrict__ Avec,
        char* __restrict__ Bp, float* __restrict__ f1, float* __restrict__ f2){
    __shared__ float fred[2][64][4];
    int t = threadIdx.x, l = t & 63, wid = t >> 6;
    int wr = wid >> 2, wc = wid & 3;
    int lg = l >> 4, lr = l & 15;
    size_t i0 = (size_t)blockIdx.x * 64;
    f32x4 acc[2][4] = {};
    for (int k0 = 0; k0 < FF; k0 += 32){
        f16x8 a[2], bf[4];
        #pragma unroll
        for (int m = 0; m < 2; ++m){
            int4 v = *(const int4*)&hin[(i0 + wr*32 + m*16 + lr)*FF + k0 + lg*8];
            a[m] = *(f16x8*)&v;
        }
        #pragma unroll
        for (int n = 0; n < 4; ++n){
            int4 v = *(const int4*)&Wt[(size_t)(wc*64 + n*16 + lr)*FF + k0 + lg*8];
            bf[n] = *(f16x8*)&v;
        }
        #pragma unroll
        for (int m = 0; m < 2; ++m)
            #pragma unroll
            for (int n = 0; n < 4; ++n)
                acc[m][n] = __builtin_amdgcn_mfma_f32_16x16x32_f16(a[m], bf[n], acc[m][n], 0, 0, 0);
    }
    // fragment-major B' store
    int b   = (int)(i0 >> 11);
    int i0l = (int)(i0 & (NN-1));
    char* Bpb = Bp + ((size_t)b << 20);            // b * 16*64*1024
    int kb  = (i0l >> 5) + wr;
    #pragma unroll
    for (int m = 0; m < 2; ++m){
        int lgp = m*2 + (lg >> 1);
        int eb  = (lg & 1)*4;
        #pragma unroll
        for (int n = 0; n < 4; ++n){
            union { _Float16 h[4]; u64 u; } pk;
            pk.h[0] = (_Float16)acc[m][n][0]; pk.h[1] = (_Float16)acc[m][n][1];
            pk.h[2] = (_Float16)acc[m][n][2]; pk.h[3] = (_Float16)acc[m][n][3];
            int c16 = wc*4 + n;
            size_t off = ((size_t)(c16*64 + kb) << 10) + (size_t)((lgp*16 + lr)*16 + eb*2);
            *(u64*)(Bpb + off) = pk.u;
        }
    }
    // fused f1/f2 (fp32 from accumulators), scaled by log2(e)
    float a1v[4], a2v[4];
    #pragma unroll
    for (int n = 0; n < 4; ++n){
        a1v[n] = Avec[wc*64 + n*16 + lr];
        a2v[n] = Avec[FF + wc*64 + n*16 + lr];
    }
    #pragma unroll
    for (int m = 0; m < 2; ++m){
        #pragma unroll
        for (int q = 0; q < 4; ++q){
            float p1 = 0.f, p2 = 0.f;
            #pragma unroll
            for (int n = 0; n < 4; ++n){
                float v = acc[m][n][q];
                p1 = fmaf(v, a1v[n], p1);
                p2 = fmaf(v, a2v[n], p2);
            }
            #pragma unroll
            for (int msk = 1; msk < 16; msk <<= 1){
                p1 += __shfl_xor(p1, msk);
                p2 += __shfl_xor(p2, msk);
            }
            if (lr == 0){
                fred[0][wr*32 + m*16 + lg*4 + q][wc] = p1;
                fred[1][wr*32 + m*16 + lg*4 + q][wc] = p2;
            }
        }
    }
    __syncthreads();
    if (t < 128){
        int row = t & 63, f = t >> 6;
        float v = fred[f][row][0] + fred[f][row][1] + fred[f][row][2] + fred[f][row][3];
        (f ? f2 : f1)[i0 + row] = v * L2E;
    }
}

// ---------------------------------------------------------------- g[b][j] = -log2( sum_i adj ? 2^(lrelu(f1s_i+f2s_j)) : 0 )
// grid 512 (b = blk>>6, 64 j-tiles of 32), 2 blocks/CU; two-stage padded LDS reduce.
__global__ __launch_bounds__(512,2) void spass_g(const u64* __restrict__ packed,
        const float* __restrict__ f1, const float* __restrict__ f2, float* __restrict__ g){
    __shared__ float sred[128][33];
    __shared__ float sred2[8][33];
    int blk = blockIdx.x, t = threadIdx.x;
    int b2 = blk >> 6, jt = blk & 63;
    const unsigned* pb32 = (const unsigned*)(packed + (size_t)b2*NN*(NW/2));
    const float* f1b = f1 + b2*NN;
    int jg = t & 3, ic = t >> 2;          // 4 j-groups x 128 i-chunks
    int j0 = jt*32 + jg*8;
    float f2v[8];
    *(float4*)&f2v[0] = *(const float4*)&f2[b2*NN + j0];
    *(float4*)&f2v[4] = *(const float4*)&f2[b2*NN + j0 + 4];
    int wi = jt, sh = jg*8;
    float acc[8] = {};
    #pragma unroll 4
    for (int ii = 0; ii < 16; ++ii){
        int i = ic*16 + ii;
        unsigned w = pb32[(size_t)i*NW + wi] >> sh;
        float f1v = f1b[i];
        #pragma unroll
        for (int e = 0; e < 8; ++e){
            float xv = f1v + f2v[e];
            float p = __builtin_amdgcn_exp2f(fmaxf(xv, ALPHA*xv));
            acc[e] += ((w >> e) & 1u) ? p : 0.f;
        }
    }
    #pragma unroll
    for (int e = 0; e < 8; ++e) sred[ic][jg*8 + e] = acc[e];
    __syncthreads();
    if (t < 256){
        int j = t & 31, part = t >> 5;
        float s = 0.f;
        #pragma unroll
        for (int k = 0; k < 16; ++k) s += sred[part*16 + k][j];
        sred2[part][j] = s;
    }
    __syncthreads();
    if (t < 32){
        float s = 0.f;
        #pragma unroll
        for (int p = 0; p < 8; ++p) s += sred2[p][t];
        g[b2*NN + jt*32 + t] = -__builtin_amdgcn_logf(s);
    }
}

// ---------------------------------------------------------------- hout = lrelu( P' @ Wh ): B' direct from L2, P' in LDS
// tile 64 rows x 256 cols; 8 waves, wave tile 64x32 (NO B duplication); grid 256: b = blk&7.
// f2/g pre-staged in LDS (FG); exp2-rebased P-gen with cvt_pkrtz packing.
__global__ __launch_bounds__(512,2) void gemm_att(const char* __restrict__ Bp,
        const u64* __restrict__ packed64, const float* __restrict__ f1,
        const float* __restrict__ f2, const float* __restrict__ g,
        _Float16* __restrict__ hnext, float* __restrict__ out, int last){
    __shared__ char Ps0[8192];
    __shared__ char Ps1[8192];
    __shared__ float FG[2][NN];      // FG[0]=f2s(b), FG[1]=g2(b): 16 KB, loaded once
    int t = threadIdx.x, l = t & 63, wid = t >> 6;
    int lg = l >> 4, lr = l & 15;
    int b  = blockIdx.x & 7;
    int i0 = (blockIdx.x >> 3) * 64;
    const char* Bpw = Bp + ((size_t)b << 20) + ((size_t)(wid*2*64) << 10) + (size_t)(l << 4);
    const u64* pb = packed64 + (size_t)b*NN*(NW/2);
    // stage f2,g for this batch into LDS (512 thr x float4 covers 2048 floats each)
    ((float4*)&FG[0][0])[t] = ((const float4*)(f2 + b*NN))[t];
    ((float4*)&FG[1][0])[t] = ((const float4*)(g  + b*NN))[t];
    // P-gen: thread owns (row = t>>3, 8 j's at (t&7)*8) of the 64x64 P tile
    int prow = t >> 3, pch = t & 7;
    float f1v = f1[b*NN + i0 + prow];
    const u64* prowp = pb + (size_t)(i0 + prow)*(NW/2);
    int pso = prow*128 + ((pch << 4) ^ ((prow & 7) << 4));

    int4 brega[4], bregb[4];
    float fv[8], gv[8];
    unsigned w8;
    f32x4 acc[4][2] = {};

    #define LOADB(reg_, ks_) do{                                                       \
        _Pragma("unroll")                                                              \
        for (int n = 0; n < 2; ++n)                                                    \
          _Pragma("unroll")                                                            \
          for (int kk = 0; kk < 2; ++kk)                                               \
            reg_[n*2+kk] = *(const int4*)(Bpw + (((size_t)(n*64 + (ks_)*2 + kk)) << 10)); \
    }while(0)

    #define LOADP(ks_) do{                                                             \
        w8 = (unsigned)(prowp[ks_] >> (pch*8)) & 0xffu;                                \
        int jb_ = (ks_)*64 + pch*8;                                                    \
        *(float4*)&fv[0] = *(const float4*)&FG[0][jb_];                                \
        *(float4*)&fv[4] = *(const float4*)&FG[0][jb_+4];                              \
        *(float4*)&gv[0] = *(const float4*)&FG[1][jb_];                                \
        *(float4*)&gv[4] = *(const float4*)&FG[1][jb_+4];                              \
    }while(0)

    #define WRITEP(pbase_) do{                                                         \
        float pf_[8];                                                                  \
        _Pragma("unroll")                                                              \
        for (int e = 0; e < 8; ++e){                                                   \
            float xv_ = f1v + fv[e];                                                   \
            float p_ = __builtin_amdgcn_exp2f(fmaxf(xv_, ALPHA*xv_) + gv[e]);          \
            pf_[e] = ((w8 >> e) & 1u) ? p_ : 0.f;                                      \
        }                                                                              \
        union { h16x2 h2[4]; f16x8 v8; } pu_;                                          \
        pu_.h2[0] = __builtin_amdgcn_cvt_pkrtz(pf_[0], pf_[1]);                        \
        pu_.h2[1] = __builtin_amdgcn_cvt_pkrtz(pf_[2], pf_[3]);                        \
        pu_.h2[2] = __builtin_amdgcn_cvt_pkrtz(pf_[4], pf_[5]);                        \
        pu_.h2[3] = __builtin_amdgcn_cvt_pkrtz(pf_[6], pf_[7]);                        \
        *(f16x8*)((pbase_) + pso) = pu_.v8;                                            \
    }while(0)

    #define MFMA_STEP(reg_, pbase_) do{                                                \
        f16x8 pa_[4][2];                                                               \
        _Pragma("unroll")                                                              \
        for (int m = 0; m < 4; ++m){                                                   \
            int row_ = m*16 + lr;                                                      \
            _Pragma("unroll")                                                          \
            for (int kk = 0; kk < 2; ++kk)                                             \
                pa_[m][kk] = *(const f16x8*)((pbase_) + row_*128 + (((kk*4 + lg) << 4) ^ ((row_ & 7) << 4))); \
        }                                                                              \
        _Pragma("unroll")                                                              \
        for (int n = 0; n < 2; ++n)                                                    \
          _Pragma("unroll")                                                            \
          for (int kk = 0; kk < 2; ++kk){                                              \
            f16x8 bf_ = *(const f16x8*)&reg_[n*2+kk];                                  \
            _Pragma("unroll")                                                          \
            for (int m = 0; m < 4; ++m)                                                \
                acc[m][n] = __builtin_amdgcn_mfma_f32_16x16x32_f16(pa_[m][kk], bf_, acc[m][n], 0, 0, 0); \
          }                                                                            \
    }while(0)

    LOADB(brega, 0);
    __syncthreads();                 // FG staged
    LOADP(0); WRITEP(Ps0);
    __syncthreads();
    for (int ks2 = 0; ks2 < 16; ++ks2){
        int s = 2*ks2;
        // even step: consume brega/Ps0; prefetch s+1 into bregb; P(s+1) -> Ps1
        LOADB(bregb, s+1); LOADP(s+1);
        MFMA_STEP(brega, Ps0);
        WRITEP(Ps1);
        __syncthreads();
        // odd step: consume bregb/Ps1; prefetch s+2 into brega; P(s+2) -> Ps0
        if (ks2 < 15){ LOADB(brega, s+2); LOADP(s+2); }
        MFMA_STEP(bregb, Ps1);
        if (ks2 < 15){ WRITEP(Ps0); __syncthreads(); }
    }
    #undef LOADB
    #undef LOADP
    #undef WRITEP
    #undef MFMA_STEP

    size_t obase = (size_t)b*NN*FF;
    #pragma unroll
    for (int m = 0; m < 4; ++m){
        #pragma unroll
        for (int q = 0; q < 4; ++q){
            size_t row = i0 + m*16 + lg*4 + q;
            #pragma unroll
            for (int n = 0; n < 2; ++n){
                int col = wid*32 + n*16 + lr;
                float v = lrelu(acc[m][n][q]);
                if (last) out[obase + row*FF + col] = v;
                else      hnext[obase + row*FF + col] = (_Float16)v;
            }
        }
    }
}

// ----------------------------------------------------------------
extern "C" void kernel_launch(void* const* d_in, const int* in_sizes, int n_in,
                              void* d_out, int out_size, void* d_ws, size_t ws_size,
                              hipStream_t stream){
    const float* x     = (const float*)d_in[0];
    const int*   adj   = (const int*)  d_in[1];
    const float* W0    = (const float*)d_in[2];
    const float* Wrest = (const float*)d_in[3];
    const float* A     = (const float*)d_in[4];
    float* out = (float*)d_out;

    char* ws = (char*)d_ws;
    size_t off = 0;
    auto carve = [&](size_t bytes) -> void* {
        void* p = ws + off;
        off += (bytes + 255) & ~(size_t)255;
        return p;
    };
    u64*      packed = (u64*)     carve((size_t)BB*NN*NN/8);
    _Float16* hA     = (_Float16*)carve((size_t)BB*NN*FF*2);
    _Float16* hB     = (_Float16*)carve((size_t)BB*NN*FF*2);
    char*     Bp     = (char*)    carve((size_t)BB*NN*FF*2);   // fragment-major Wh panels
    _Float16* Wt     = (_Float16*)carve((size_t)4*FF*FF*2);
    float*    f1     = (float*)   carve((size_t)BB*NN*4);
    float*    f2     = (float*)   carve((size_t)BB*NN*4);
    float*    g      = (float*)   carve((size_t)BB*NN*4);

    pack_prep<<<2048, 256, 0, stream>>>(adj, packed, x, hA, W0, Wrest, Wt);

    _Float16* bufs[2] = {hA, hB};
    const _Float16* hin = hA;
    for (int layer = 0; layer < 4; ++layer){
        const float* Al = A + (size_t)layer*2*FF;
        gemm_hw<<<256, 512, 0, stream>>>(hin, Wt + (size_t)layer*FF*FF, Al, Bp, f1, f2);
        spass_g<<<512, 512, 0, stream>>>(packed, f1, f2, g);
        int last = (layer == 3);
        _Float16* hnext = bufs[(layer + 1) & 1];
        gemm_att<<<256, 512, 0, stream>>>(Bp, packed, f1, f2, g, hnext, out, last);
        hin = hnext;
    }
}